// Round 15
// baseline (124.759 us; speedup 1.0000x reference)
//
#include <hip/hip_runtime.h>
#include <hip/hip_fp16.h>
#include <math.h>

// Problem constants (from reference)
#define BATCH 128
#define NI    1152
#define ND    8
#define NC    32
#define NE    16
#define NROUT 3

// Structure: prep kernel converts W -> fp16 lane-ordered W_h in ws (once per
// call). Route kernels read W_h DIRECTLY from global, perfectly coalesced:
// no LDS, no barriers, no staging. 256 thr = 32c x 2eh x 4bp; NB=4.
// ISPLIT=48 -> ws = 9.44 (W_h) + 6.29 (fp16 partials) + 0.26 (o_sum)
//            = 15.99 MB < 17.04 MB proven-available floor.
#define ISPLIT     48
#define ICHUNK     (NI / ISPLIT)    // 24
#define BT         16
#define NB         4
#define RT_THREADS 256
#define SQ_THREADS 256
#define PREP_TPB   2                // W tiles per prep block

typedef _Float16 h2 __attribute__((ext_vector_type(2)));
typedef unsigned int uint;

// cvt_pkrtz returns a __fp16 vector; bit-cast to h2 (_Float16 vector).
__device__ __forceinline__ h2 cvt_pk(float a, float b) {
    auto r = __builtin_amdgcn_cvt_pkrtz(a, b);
    union { decltype(r) i; h2 o; } u; u.i = r; return u.o;
}
__device__ __forceinline__ uint h2u(h2 v) { union { h2 h; uint u; } x; x.h = v; return x.u; }
__device__ __forceinline__ h2 u2h(uint v) { union { uint u; h2 h; } x; x.u = v; return x.h; }

#if __has_builtin(__builtin_amdgcn_fdot2)
#define FDOT2(a, b, c) __builtin_amdgcn_fdot2((a), (b), (c), false)
#else
__device__ __forceinline__ float FDOT2(h2 a, h2 b, float c) {
    return c + (float)a.x * (float)b.x + (float)a.y * (float)b.y;
}
#endif

template<int CTRL>
__device__ __forceinline__ float dpp_add(float v) {
    int t = __builtin_amdgcn_update_dpp(0, __float_as_int(v), CTRL, 0xF, 0xF, true);
    return v + __int_as_float(t);
}

// v[i] + v[i^32] — VALU permlane (fallback: shfl)
__device__ __forceinline__ float xor32_sum(float v) {
#if __has_builtin(__builtin_amdgcn_permlane32_swap)
    auto r = __builtin_amdgcn_permlane32_swap(__float_as_int(v), __float_as_int(v), false, false);
    return __int_as_float(r[0]) + __int_as_float(r[1]);
#else
    return v + __shfl_xor(v, 32);
#endif
}
// v[i] + v[i^16] — VALU permlane (fallback: ds_swizzle)
__device__ __forceinline__ float xor16_sum(float v) {
#if __has_builtin(__builtin_amdgcn_permlane16_swap)
    auto r = __builtin_amdgcn_permlane16_swap(__float_as_int(v), __float_as_int(v), false, false);
    return __int_as_float(r[0]) + __int_as_float(r[1]);
#else
    int s = __builtin_amdgcn_ds_swizzle(__float_as_int(v), 0x401F);
    return v + __int_as_float(s);
#endif
}

// Sum over lane bits 0..2 (8 e-pair lanes) for squash.
__device__ __forceinline__ float sum_over_e8(float v) {
    v = dpp_add<0xB1>(v);
    v = dpp_add<0x4E>(v);
    v = dpp_add<0x141>(v);
    return v;
}

// ---------------------------------------------------------------------------
// prep: W[i][c][d][e] fp32 -> W_h[i][er][eh][c] uint4 (4 d-pair h2's).
// Read coalesced -> LDS (padded, transposed-on-read) -> coalesced uint4 out.
// Lane-ordered layout: route's per-instruction W reads become 64 consecutive
// uint4 (1 KB) per wave.
// ---------------------------------------------------------------------------
__global__ __launch_bounds__(RT_THREADS)
void prep_kernel(const float* __restrict__ W, uint4* __restrict__ W_h)
{
    __shared__ float ls[PREP_TPB][NC * 132];   // 33.8 KB (c-row stride 132)

    const int tid = threadIdx.x;
    const size_t i0 = (size_t)blockIdx.x * PREP_TPB;

    const float4* src = (const float4*)(W + i0 * (NC * ND * NE));
#pragma unroll
    for (int t = 0; t < PREP_TPB; ++t) {
#pragma unroll
        for (int r = 0; r < 4; ++r) {
            int g = tid + r * RT_THREADS;              // 1024 float4 per tile
            float4 v = src[t * 1024 + g];
            *(float4*)&ls[t][(g >> 5) * 132 + (g & 31) * 4] = v;
        }
    }
    __syncthreads();

#pragma unroll
    for (int t = 0; t < PREP_TPB; ++t) {
#pragma unroll
        for (int r = 0; r < 2; ++r) {
            int g  = tid + r * RT_THREADS;             // 512 outputs per tile
            int er = g >> 6, ehh = (g >> 5) & 1, c = g & 31;
            int e  = ehh * 8 + er;
            const float* p = &ls[t][c * 132 + e];      // stride 16 over d
            uint4 o;
            o.x = h2u(cvt_pk(p[0],  p[16]));
            o.y = h2u(cvt_pk(p[32], p[48]));
            o.z = h2u(cvt_pk(p[64], p[80]));
            o.w = h2u(cvt_pk(p[96], p[112]));
            W_h[(i0 + t) * 512 + g] = o;
        }
    }
}

// ---------------------------------------------------------------------------
// route: barrier-free, LDS-free. Per ii: 8 coalesced uint4 W_h loads,
// 128 v_dot2, all-VALU softmax, register s accumulation. fp16 partial out.
// ---------------------------------------------------------------------------
__global__ __launch_bounds__(RT_THREADS)
void route_iter_kernel(const float* __restrict__ x, const uint4* __restrict__ W_h,
                       const float* __restrict__ o_sum, __half* __restrict__ s_part,
                       int iter)
{
    const int tid = threadIdx.x;
    const int c   = tid & 31;
    const int eh  = (tid >> 5) & 1;
    int wid;   // laundered wave id -> x addresses stay on the vector path
    asm("v_mov_b32 %0, %1" : "=v"(wid) : "v"(tid >> 6));
    const int ic  = blockIdx.x;
    const int bt  = blockIdx.y;
    const int i0  = ic * ICHUNK;
    const int b0  = bt * BT + wid * NB;
    const int e0  = eh * 8;

    // o_sum[b, c, e0..e0+7] in registers (iter > 0 only)
    float o_reg[NB][8];
    if (iter > 0) {
#pragma unroll
        for (int j = 0; j < NB; ++j) {
            const float4* op = (const float4*)(o_sum + ((size_t)(b0 + j) * NC + c) * NE + e0);
            float4 a = op[0], b = op[1];
            o_reg[j][0] = a.x; o_reg[j][1] = a.y; o_reg[j][2] = a.z; o_reg[j][3] = a.w;
            o_reg[j][4] = b.x; o_reg[j][5] = b.y; o_reg[j][6] = b.z; o_reg[j][7] = b.w;
        }
    }

    float s_acc[NB][8];
#pragma unroll
    for (int j = 0; j < NB; ++j)
#pragma unroll
        for (int e = 0; e < 8; ++e) s_acc[j][e] = 0.f;

    // x(0) prefetch (vector loads)
    const float* xp[NB];
    float4 xnA[NB][2], xnB[NB][2];
#pragma unroll
    for (int j = 0; j < NB; ++j) {
        xp[j] = x + ((size_t)(b0 + j) * NI + i0) * ND;
        xnA[j][0] = *(const float4*)xp[j];
        xnA[j][1] = *(const float4*)(xp[j] + 4);
    }

    // per-thread W_h base: lane (c,eh) -> consecutive uint4 across the wave
    const uint4* wp = W_h + (size_t)i0 * 512 + eh * 32 + c;

    auto body = [&](const float4 (&XC)[NB][2], float4 (&XN)[NB][2], int II) {
        // issue all 8 W loads for this ii
        uint4 wv[8];
#pragma unroll
        for (int er = 0; er < 8; ++er) wv[er] = wp[er * 64];
        wp += 512;

        // issue x(II+1) into the other x register buffer
        if (II + 1 < ICHUNK) {
#pragma unroll
            for (int j = 0; j < NB; ++j) {
                xp[j] += ND;
                XN[j][0] = *(const float4*)xp[j];
                XN[j][1] = *(const float4*)(xp[j] + 4);
            }
        }

        // x -> half2 d-pairs
        h2 xq[NB][4];
#pragma unroll
        for (int j = 0; j < NB; ++j) {
            xq[j][0] = cvt_pk(XC[j][0].x, XC[j][0].y);
            xq[j][1] = cvt_pk(XC[j][0].z, XC[j][0].w);
            xq[j][2] = cvt_pk(XC[j][1].x, XC[j][1].y);
            xq[j][3] = cvt_pk(XC[j][1].z, XC[j][1].w);
        }

        // ---- u_hat (128 dot2) ----
        float uh[NB][8];
#pragma unroll
        for (int er = 0; er < 8; ++er) {
            h2 w0 = u2h(wv[er].x), w1 = u2h(wv[er].y);
            h2 w2 = u2h(wv[er].z), w3 = u2h(wv[er].w);
#pragma unroll
            for (int j = 0; j < NB; ++j) {
                float acc = 0.f;
                acc = FDOT2(xq[j][0], w0, acc);
                acc = FDOT2(xq[j][1], w1, acc);
                acc = FDOT2(xq[j][2], w2, acc);
                acc = FDOT2(xq[j][3], w3, acc);
                uh[j][er] = acc;
            }
        }

        // ---- routing weights + s accumulation (all-VALU reductions) ----
        if (iter > 0) {
#pragma unroll
            for (int j = 0; j < NB; ++j) {
                float lp = 0.f;
#pragma unroll
                for (int e = 0; e < 8; ++e) lp = fmaf(uh[j][e], o_reg[j][e], lp);
                lp = xor32_sum(lp);                 // combine e-halves
                float el = __expf(lp);              // |logit| small; no max-sub
                float v = dpp_add<0x140>(dpp_add<0x141>(
                          dpp_add<0x4E>(dpp_add<0xB1>(el))));
                float den = xor16_sum(v);           // softmax denom over 32 c
                float wgt = el * __builtin_amdgcn_rcpf(den);
#pragma unroll
                for (int e = 0; e < 8; ++e) s_acc[j][e] = fmaf(wgt, uh[j][e], s_acc[j][e]);
            }
        } else {
            const float wgt = 1.f / 32.f;
#pragma unroll
            for (int j = 0; j < NB; ++j)
#pragma unroll
                for (int e = 0; e < 8; ++e) s_acc[j][e] = fmaf(wgt, uh[j][e], s_acc[j][e]);
        }
    };

    // 24 iterations, A/B x-buffer alternation (unroll pairs)
    for (int r2 = 0; r2 < ICHUNK / 2; ++r2) {
        body(xnA, xnB, 2 * r2);
        body(xnB, xnA, 2 * r2 + 1);
    }

    // ---- write partial s (fp16, one slice per ic) ----
#pragma unroll
    for (int j = 0; j < NB; ++j) {
        __half* base = s_part + (((size_t)ic * BATCH + (b0 + j)) * NC + c) * NE + e0;
        union { __half2 h2v[4]; uint4 u; } pk;
#pragma unroll
        for (int q = 0; q < 4; ++q)
            pk.h2v[q] = __floats2half2_rn(s_acc[j][2*q], s_acc[j][2*q+1]);
        *(uint4*)base = pk.u;
    }
}

// ---------------------------------------------------------------------------
// squash: reduce 48 fp16 slices, squash, update o_sum / write output.
// Each thread owns an e-pair; DPP e-reduction over lane bits 0..2.
// ---------------------------------------------------------------------------
__global__ __launch_bounds__(SQ_THREADS)
void squash_kernel(const __half* __restrict__ s_part, float* __restrict__ o_sum,
                   float* __restrict__ out, int iter)
{
    const int base2 = (blockIdx.x * SQ_THREADS + threadIdx.x) * 2;  // element pair

    float a0 = 0.f, a1 = 0.f;
#pragma unroll 8
    for (int k = 0; k < ISPLIT; ++k) {
        __half2 v = *(const __half2*)(s_part + (size_t)k * (BATCH * NC * NE) + base2);
        a0 += __low2float(v);
        a1 += __high2float(v);
    }

    float q = sum_over_e8(a0 * a0 + a1 * a1);
    // scale = s2/(1+s2)/sqrt(s2) == sqrt(s2)/(1+s2)
    float scale = sqrtf(q) / (1.f + q);
    float o0 = scale * a0, o1 = scale * a1;

    if (iter == NROUT - 1) {
        *(float2*)(out + base2) = make_float2(o0, o1);
    } else if (iter == 0) {
        *(float2*)(o_sum + base2) = make_float2(o0, o1);
    } else {
        float2 prev = *(float2*)(o_sum + base2);
        *(float2*)(o_sum + base2) = make_float2(prev.x + o0, prev.y + o1);
    }
}

extern "C" void kernel_launch(void* const* d_in, const int* in_sizes, int n_in,
                              void* d_out, int out_size, void* d_ws, size_t ws_size,
                              hipStream_t stream) {
    const float* x = (const float*)d_in[0];   // [128,1152,8]
    const float* W = (const float*)d_in[1];   // [1152,32,8,16]
    float* out = (float*)d_out;               // [128,32,16]

    // ws layout: [W_h 9.44 MB][s_part fp16 6.29 MB][o_sum 0.26 MB] = 15.99 MB
    uint4*  W_h    = (uint4*)d_ws;                                   // 1152*512 uint4
    __half* s_part = (__half*)(W_h + (size_t)NI * 512);              // 48*65536 half
    float*  o_sum  = (float*)(s_part + (size_t)ISPLIT * BATCH * NC * NE);

    prep_kernel<<<NI / PREP_TPB, RT_THREADS, 0, stream>>>(W, W_h);

    for (int it = 0; it < NROUT; ++it) {
        route_iter_kernel<<<dim3(ISPLIT, BATCH / BT), RT_THREADS, 0, stream>>>(
            x, W_h, o_sum, s_part, it);
        squash_kernel<<<(BATCH * NC * NE) / (SQ_THREADS * 2), SQ_THREADS, 0, stream>>>(
            s_part, o_sum, out, it);
    }
}

// Round 16
// 120.096 us; speedup vs baseline: 1.0388x; 1.0388x over previous
//
#include <hip/hip_runtime.h>
#include <hip/hip_fp16.h>
#include <math.h>

// Problem constants (from reference)
#define BATCH 128
#define NI    1152
#define ND    8
#define NC    32
#define NE    16
#define NROUT 3

// Structure: prep kernel converts W -> fp16 lane-ordered W_h in ws (once per
// call). Route kernels read W_h DIRECTLY from global, perfectly coalesced,
// DOUBLE-BUFFERED in registers (w loads issued one full body ahead).
// No LDS, no barriers. 256 thr = 32c x 2eh x 4bp; NB=4.
// ISPLIT=48 -> ws = 9.44 (W_h) + 6.29 (fp16 partials) + 0.26 (o_sum) = 15.99 MB.
#define ISPLIT     48
#define ICHUNK     (NI / ISPLIT)    // 24
#define BT         16
#define NB         4
#define RT_THREADS 256
#define SQ_THREADS 256
#define PREP_TPB   2                // W tiles per prep block

typedef _Float16 h2 __attribute__((ext_vector_type(2)));
typedef unsigned int uint;

// cvt_pkrtz returns a __fp16 vector; bit-cast to h2 (_Float16 vector).
__device__ __forceinline__ h2 cvt_pk(float a, float b) {
    auto r = __builtin_amdgcn_cvt_pkrtz(a, b);
    union { decltype(r) i; h2 o; } u; u.i = r; return u.o;
}
__device__ __forceinline__ uint h2u(h2 v) { union { h2 h; uint u; } x; x.h = v; return x.u; }
__device__ __forceinline__ h2 u2h(uint v) { union { uint u; h2 h; } x; x.u = v; return x.h; }

#if __has_builtin(__builtin_amdgcn_fdot2)
#define FDOT2(a, b, c) __builtin_amdgcn_fdot2((a), (b), (c), false)
#else
__device__ __forceinline__ float FDOT2(h2 a, h2 b, float c) {
    return c + (float)a.x * (float)b.x + (float)a.y * (float)b.y;
}
#endif

template<int CTRL>
__device__ __forceinline__ float dpp_add(float v) {
    int t = __builtin_amdgcn_update_dpp(0, __float_as_int(v), CTRL, 0xF, 0xF, true);
    return v + __int_as_float(t);
}

// v[i] + v[i^32] — VALU permlane (fallback: shfl)
__device__ __forceinline__ float xor32_sum(float v) {
#if __has_builtin(__builtin_amdgcn_permlane32_swap)
    auto r = __builtin_amdgcn_permlane32_swap(__float_as_int(v), __float_as_int(v), false, false);
    return __int_as_float(r[0]) + __int_as_float(r[1]);
#else
    return v + __shfl_xor(v, 32);
#endif
}
// v[i] + v[i^16] — VALU permlane (fallback: ds_swizzle)
__device__ __forceinline__ float xor16_sum(float v) {
#if __has_builtin(__builtin_amdgcn_permlane16_swap)
    auto r = __builtin_amdgcn_permlane16_swap(__float_as_int(v), __float_as_int(v), false, false);
    return __int_as_float(r[0]) + __int_as_float(r[1]);
#else
    int s = __builtin_amdgcn_ds_swizzle(__float_as_int(v), 0x401F);
    return v + __int_as_float(s);
#endif
}

// Sum over lane bits 0..2 (8 e-pair lanes) for squash.
__device__ __forceinline__ float sum_over_e8(float v) {
    v = dpp_add<0xB1>(v);
    v = dpp_add<0x4E>(v);
    v = dpp_add<0x141>(v);
    return v;
}

// ---------------------------------------------------------------------------
// prep: W[i][c][d][e] fp32 -> W_h[i][er][eh][c] uint4 (4 d-pair h2's).
// ---------------------------------------------------------------------------
__global__ __launch_bounds__(RT_THREADS)
void prep_kernel(const float* __restrict__ W, uint4* __restrict__ W_h)
{
    __shared__ float ls[PREP_TPB][NC * 132];   // 33.8 KB (c-row stride 132)

    const int tid = threadIdx.x;
    const size_t i0 = (size_t)blockIdx.x * PREP_TPB;

    const float4* src = (const float4*)(W + i0 * (NC * ND * NE));
#pragma unroll
    for (int t = 0; t < PREP_TPB; ++t) {
#pragma unroll
        for (int r = 0; r < 4; ++r) {
            int g = tid + r * RT_THREADS;              // 1024 float4 per tile
            float4 v = src[t * 1024 + g];
            *(float4*)&ls[t][(g >> 5) * 132 + (g & 31) * 4] = v;
        }
    }
    __syncthreads();

#pragma unroll
    for (int t = 0; t < PREP_TPB; ++t) {
#pragma unroll
        for (int r = 0; r < 2; ++r) {
            int g  = tid + r * RT_THREADS;             // 512 outputs per tile
            int er = g >> 6, ehh = (g >> 5) & 1, c = g & 31;
            int e  = ehh * 8 + er;
            const float* p = &ls[t][c * 132 + e];      // stride 16 over d
            uint4 o;
            o.x = h2u(cvt_pk(p[0],  p[16]));
            o.y = h2u(cvt_pk(p[32], p[48]));
            o.z = h2u(cvt_pk(p[64], p[80]));
            o.w = h2u(cvt_pk(p[96], p[112]));
            W_h[(i0 + t) * 512 + g] = o;
        }
    }
}

// ---------------------------------------------------------------------------
// route: barrier-free, LDS-free, register double-buffered W AND x.
// Per ii: issue next tile's 8 uint4 W loads, then 128 v_dot2 on current,
// all-VALU softmax, register s accumulation. fp16 partial out.
// ---------------------------------------------------------------------------
__global__ __launch_bounds__(RT_THREADS)
void route_iter_kernel(const float* __restrict__ x, const uint4* __restrict__ W_h,
                       const float* __restrict__ o_sum, __half* __restrict__ s_part,
                       int iter)
{
    const int tid = threadIdx.x;
    const int c   = tid & 31;
    const int eh  = (tid >> 5) & 1;
    int wid;   // laundered wave id -> x addresses stay on the vector path
    asm("v_mov_b32 %0, %1" : "=v"(wid) : "v"(tid >> 6));
    const int ic  = blockIdx.x;
    const int bt  = blockIdx.y;
    const int i0  = ic * ICHUNK;
    const int b0  = bt * BT + wid * NB;
    const int e0  = eh * 8;

    // o_sum[b, c, e0..e0+7] in registers (iter > 0 only)
    float o_reg[NB][8];
    if (iter > 0) {
#pragma unroll
        for (int j = 0; j < NB; ++j) {
            const float4* op = (const float4*)(o_sum + ((size_t)(b0 + j) * NC + c) * NE + e0);
            float4 a = op[0], b = op[1];
            o_reg[j][0] = a.x; o_reg[j][1] = a.y; o_reg[j][2] = a.z; o_reg[j][3] = a.w;
            o_reg[j][4] = b.x; o_reg[j][5] = b.y; o_reg[j][6] = b.z; o_reg[j][7] = b.w;
        }
    }

    float s_acc[NB][8];
#pragma unroll
    for (int j = 0; j < NB; ++j)
#pragma unroll
        for (int e = 0; e < 8; ++e) s_acc[j][e] = 0.f;

    // per-thread W_h base: lane (c,eh) -> consecutive uint4 across the wave
    const uint4* wp = W_h + (size_t)i0 * 512 + eh * 32 + c;

    // ---- prologue: x(0) and W(0) in flight ----
    const float* xp[NB];
    float4 xnA[NB][2], xnB[NB][2];
#pragma unroll
    for (int j = 0; j < NB; ++j) {
        xp[j] = x + ((size_t)(b0 + j) * NI + i0) * ND;
        xnA[j][0] = *(const float4*)xp[j];
        xnA[j][1] = *(const float4*)(xp[j] + 4);
    }
    uint4 wvA[8], wvB[8];
#pragma unroll
    for (int er = 0; er < 8; ++er) wvA[er] = wp[er * 64];
    wp += 512;

    auto body = [&](const float4 (&XC)[NB][2], float4 (&XN)[NB][2],
                    const uint4 (&WC)[8], uint4 (&WN)[8], int II) {
        // issue NEXT tile's W loads first (a full body of compute to land)
        if (II + 1 < ICHUNK) {
#pragma unroll
            for (int er = 0; er < 8; ++er) WN[er] = wp[er * 64];
            wp += 512;
            // issue x(II+1)
#pragma unroll
            for (int j = 0; j < NB; ++j) {
                xp[j] += ND;
                XN[j][0] = *(const float4*)xp[j];
                XN[j][1] = *(const float4*)(xp[j] + 4);
            }
        }

        // x -> half2 d-pairs
        h2 xq[NB][4];
#pragma unroll
        for (int j = 0; j < NB; ++j) {
            xq[j][0] = cvt_pk(XC[j][0].x, XC[j][0].y);
            xq[j][1] = cvt_pk(XC[j][0].z, XC[j][0].w);
            xq[j][2] = cvt_pk(XC[j][1].x, XC[j][1].y);
            xq[j][3] = cvt_pk(XC[j][1].z, XC[j][1].w);
        }

        // ---- u_hat (128 dot2) on current W registers ----
        float uh[NB][8];
#pragma unroll
        for (int er = 0; er < 8; ++er) {
            h2 w0 = u2h(WC[er].x), w1 = u2h(WC[er].y);
            h2 w2 = u2h(WC[er].z), w3 = u2h(WC[er].w);
#pragma unroll
            for (int j = 0; j < NB; ++j) {
                float acc = 0.f;
                acc = FDOT2(xq[j][0], w0, acc);
                acc = FDOT2(xq[j][1], w1, acc);
                acc = FDOT2(xq[j][2], w2, acc);
                acc = FDOT2(xq[j][3], w3, acc);
                uh[j][er] = acc;
            }
        }

        // ---- routing weights + s accumulation (all-VALU reductions) ----
        if (iter > 0) {
#pragma unroll
            for (int j = 0; j < NB; ++j) {
                float lp = 0.f;
#pragma unroll
                for (int e = 0; e < 8; ++e) lp = fmaf(uh[j][e], o_reg[j][e], lp);
                lp = xor32_sum(lp);                 // combine e-halves
                float el = __expf(lp);              // |logit| small; no max-sub
                float v = dpp_add<0x140>(dpp_add<0x141>(
                          dpp_add<0x4E>(dpp_add<0xB1>(el))));
                float den = xor16_sum(v);           // softmax denom over 32 c
                float wgt = el * __builtin_amdgcn_rcpf(den);
#pragma unroll
                for (int e = 0; e < 8; ++e) s_acc[j][e] = fmaf(wgt, uh[j][e], s_acc[j][e]);
            }
        } else {
            const float wgt = 1.f / 32.f;
#pragma unroll
            for (int j = 0; j < NB; ++j)
#pragma unroll
                for (int e = 0; e < 8; ++e) s_acc[j][e] = fmaf(wgt, uh[j][e], s_acc[j][e]);
        }
    };

    // 24 iterations, A/B double-buffer alternation for BOTH x and W
    for (int r2 = 0; r2 < ICHUNK / 2; ++r2) {
        body(xnA, xnB, wvA, wvB, 2 * r2);
        body(xnB, xnA, wvB, wvA, 2 * r2 + 1);
    }

    // ---- write partial s (fp16, one slice per ic) ----
#pragma unroll
    for (int j = 0; j < NB; ++j) {
        __half* base = s_part + (((size_t)ic * BATCH + (b0 + j)) * NC + c) * NE + e0;
        union { __half2 h2v[4]; uint4 u; } pk;
#pragma unroll
        for (int q = 0; q < 4; ++q)
            pk.h2v[q] = __floats2half2_rn(s_acc[j][2*q], s_acc[j][2*q+1]);
        *(uint4*)base = pk.u;
    }
}

// ---------------------------------------------------------------------------
// squash: reduce 48 fp16 slices, squash, update o_sum / write output.
// ---------------------------------------------------------------------------
__global__ __launch_bounds__(SQ_THREADS)
void squash_kernel(const __half* __restrict__ s_part, float* __restrict__ o_sum,
                   float* __restrict__ out, int iter)
{
    const int base2 = (blockIdx.x * SQ_THREADS + threadIdx.x) * 2;  // element pair

    float a0 = 0.f, a1 = 0.f;
#pragma unroll 8
    for (int k = 0; k < ISPLIT; ++k) {
        __half2 v = *(const __half2*)(s_part + (size_t)k * (BATCH * NC * NE) + base2);
        a0 += __low2float(v);
        a1 += __high2float(v);
    }

    float q = sum_over_e8(a0 * a0 + a1 * a1);
    // scale = s2/(1+s2)/sqrt(s2) == sqrt(s2)/(1+s2)
    float scale = sqrtf(q) / (1.f + q);
    float o0 = scale * a0, o1 = scale * a1;

    if (iter == NROUT - 1) {
        *(float2*)(out + base2) = make_float2(o0, o1);
    } else if (iter == 0) {
        *(float2*)(o_sum + base2) = make_float2(o0, o1);
    } else {
        float2 prev = *(float2*)(o_sum + base2);
        *(float2*)(o_sum + base2) = make_float2(prev.x + o0, prev.y + o1);
    }
}

extern "C" void kernel_launch(void* const* d_in, const int* in_sizes, int n_in,
                              void* d_out, int out_size, void* d_ws, size_t ws_size,
                              hipStream_t stream) {
    const float* x = (const float*)d_in[0];   // [128,1152,8]
    const float* W = (const float*)d_in[1];   // [1152,32,8,16]
    float* out = (float*)d_out;               // [128,32,16]

    // ws layout: [W_h 9.44 MB][s_part fp16 6.29 MB][o_sum 0.26 MB] = 15.99 MB
    uint4*  W_h    = (uint4*)d_ws;                                   // 1152*512 uint4
    __half* s_part = (__half*)(W_h + (size_t)NI * 512);              // 48*65536 half
    float*  o_sum  = (float*)(s_part + (size_t)ISPLIT * BATCH * NC * NE);

    prep_kernel<<<NI / PREP_TPB, RT_THREADS, 0, stream>>>(W, W_h);

    for (int it = 0; it < NROUT; ++it) {
        route_iter_kernel<<<dim3(ISPLIT, BATCH / BT), RT_THREADS, 0, stream>>>(
            x, W_h, o_sum, s_part, it);
        squash_kernel<<<(BATCH * NC * NE) / (SQ_THREADS * 2), SQ_THREADS, 0, stream>>>(
            s_part, o_sum, out, it);
    }
}

// Round 17
// 114.498 us; speedup vs baseline: 1.0896x; 1.0489x over previous
//
#include <hip/hip_runtime.h>
#include <hip/hip_fp16.h>
#include <math.h>

// Problem constants (from reference)
#define BATCH 128
#define NI    1152
#define ND    8
#define NC    32
#define NE    16
#define NROUT 3

// Structure: prep converts W -> fp16 lane-ordered W_h in ws (once per call).
// Route reads W_h DIRECTLY from global, coalesced, register double-buffered.
// No LDS, no barriers. 256 thr = 32c x 2eh x 4 wave-groups; NB=2 batches each
// -> grid 48 x 16 = 768 blocks = 3072 waves = 12 waves/CU (3/SIMD).
#define ISPLIT     48
#define ICHUNK     (NI / ISPLIT)    // 24
#define BT         8
#define NB         2
#define RT_THREADS 256
#define SQ_THREADS 256
#define PREP_TPB   2                // W tiles per prep block

typedef _Float16 h2 __attribute__((ext_vector_type(2)));
typedef unsigned int uint;

// cvt_pkrtz returns a __fp16 vector; bit-cast to h2 (_Float16 vector).
__device__ __forceinline__ h2 cvt_pk(float a, float b) {
    auto r = __builtin_amdgcn_cvt_pkrtz(a, b);
    union { decltype(r) i; h2 o; } u; u.i = r; return u.o;
}
__device__ __forceinline__ uint h2u(h2 v) { union { h2 h; uint u; } x; x.h = v; return x.u; }
__device__ __forceinline__ h2 u2h(uint v) { union { uint u; h2 h; } x; x.u = v; return x.h; }

#if __has_builtin(__builtin_amdgcn_fdot2)
#define FDOT2(a, b, c) __builtin_amdgcn_fdot2((a), (b), (c), false)
#else
__device__ __forceinline__ float FDOT2(h2 a, h2 b, float c) {
    return c + (float)a.x * (float)b.x + (float)a.y * (float)b.y;
}
#endif

template<int CTRL>
__device__ __forceinline__ float dpp_add(float v) {
    int t = __builtin_amdgcn_update_dpp(0, __float_as_int(v), CTRL, 0xF, 0xF, true);
    return v + __int_as_float(t);
}

// v[i] + v[i^32] — VALU permlane (fallback: shfl)
__device__ __forceinline__ float xor32_sum(float v) {
#if __has_builtin(__builtin_amdgcn_permlane32_swap)
    auto r = __builtin_amdgcn_permlane32_swap(__float_as_int(v), __float_as_int(v), false, false);
    return __int_as_float(r[0]) + __int_as_float(r[1]);
#else
    return v + __shfl_xor(v, 32);
#endif
}
// v[i] + v[i^16] — VALU permlane (fallback: ds_swizzle)
__device__ __forceinline__ float xor16_sum(float v) {
#if __has_builtin(__builtin_amdgcn_permlane16_swap)
    auto r = __builtin_amdgcn_permlane16_swap(__float_as_int(v), __float_as_int(v), false, false);
    return __int_as_float(r[0]) + __int_as_float(r[1]);
#else
    int s = __builtin_amdgcn_ds_swizzle(__float_as_int(v), 0x401F);
    return v + __int_as_float(s);
#endif
}

// Sum over lane bits 0..2 (8 e-pair lanes) for squash.
__device__ __forceinline__ float sum_over_e8(float v) {
    v = dpp_add<0xB1>(v);
    v = dpp_add<0x4E>(v);
    v = dpp_add<0x141>(v);
    return v;
}

// ---------------------------------------------------------------------------
// prep: W[i][c][d][e] fp32 -> W_h[i][er][eh][c] uint4 (4 d-pair h2's).
// ---------------------------------------------------------------------------
__global__ __launch_bounds__(RT_THREADS)
void prep_kernel(const float* __restrict__ W, uint4* __restrict__ W_h)
{
    __shared__ float ls[PREP_TPB][NC * 132];   // 33.8 KB (c-row stride 132)

    const int tid = threadIdx.x;
    const size_t i0 = (size_t)blockIdx.x * PREP_TPB;

    const float4* src = (const float4*)(W + i0 * (NC * ND * NE));
#pragma unroll
    for (int t = 0; t < PREP_TPB; ++t) {
#pragma unroll
        for (int r = 0; r < 4; ++r) {
            int g = tid + r * RT_THREADS;              // 1024 float4 per tile
            float4 v = src[t * 1024 + g];
            *(float4*)&ls[t][(g >> 5) * 132 + (g & 31) * 4] = v;
        }
    }
    __syncthreads();

#pragma unroll
    for (int t = 0; t < PREP_TPB; ++t) {
#pragma unroll
        for (int r = 0; r < 2; ++r) {
            int g  = tid + r * RT_THREADS;             // 512 outputs per tile
            int er = g >> 6, ehh = (g >> 5) & 1, c = g & 31;
            int e  = ehh * 8 + er;
            const float* p = &ls[t][c * 132 + e];      // stride 16 over d
            uint4 o;
            o.x = h2u(cvt_pk(p[0],  p[16]));
            o.y = h2u(cvt_pk(p[32], p[48]));
            o.z = h2u(cvt_pk(p[64], p[80]));
            o.w = h2u(cvt_pk(p[96], p[112]));
            W_h[(i0 + t) * 512 + g] = o;
        }
    }
}

// ---------------------------------------------------------------------------
// route: barrier-free, LDS-free, register double-buffered W and x, NB=2.
// ---------------------------------------------------------------------------
__global__ __launch_bounds__(RT_THREADS)
void route_iter_kernel(const float* __restrict__ x, const uint4* __restrict__ W_h,
                       const float* __restrict__ o_sum, __half* __restrict__ s_part,
                       int iter)
{
    const int tid = threadIdx.x;
    const int c   = tid & 31;
    const int eh  = (tid >> 5) & 1;
    int wid;   // laundered wave id -> x addresses stay on the vector path
    asm("v_mov_b32 %0, %1" : "=v"(wid) : "v"(tid >> 6));
    const int ic  = blockIdx.x;
    const int bt  = blockIdx.y;
    const int i0  = ic * ICHUNK;
    const int b0  = bt * BT + wid * NB;
    const int e0  = eh * 8;

    // o_sum[b, c, e0..e0+7] in registers (iter > 0 only)
    float o_reg[NB][8];
    if (iter > 0) {
#pragma unroll
        for (int j = 0; j < NB; ++j) {
            const float4* op = (const float4*)(o_sum + ((size_t)(b0 + j) * NC + c) * NE + e0);
            float4 a = op[0], b = op[1];
            o_reg[j][0] = a.x; o_reg[j][1] = a.y; o_reg[j][2] = a.z; o_reg[j][3] = a.w;
            o_reg[j][4] = b.x; o_reg[j][5] = b.y; o_reg[j][6] = b.z; o_reg[j][7] = b.w;
        }
    }

    float s_acc[NB][8];
#pragma unroll
    for (int j = 0; j < NB; ++j)
#pragma unroll
        for (int e = 0; e < 8; ++e) s_acc[j][e] = 0.f;

    // per-thread W_h base: lane (c,eh) -> consecutive uint4 across the wave
    const uint4* wp = W_h + (size_t)i0 * 512 + eh * 32 + c;

    // ---- prologue: x(0) and W(0) in flight ----
    const float* xp[NB];
    float4 xnA[NB][2], xnB[NB][2];
#pragma unroll
    for (int j = 0; j < NB; ++j) {
        xp[j] = x + ((size_t)(b0 + j) * NI + i0) * ND;
        xnA[j][0] = *(const float4*)xp[j];
        xnA[j][1] = *(const float4*)(xp[j] + 4);
    }
    uint4 wvA[8], wvB[8];
#pragma unroll
    for (int er = 0; er < 8; ++er) wvA[er] = wp[er * 64];
    wp += 512;

    auto body = [&](const float4 (&XC)[NB][2], float4 (&XN)[NB][2],
                    const uint4 (&WC)[8], uint4 (&WN)[8], int II) {
        // issue NEXT tile's loads first (a full body of compute to land)
        if (II + 1 < ICHUNK) {
#pragma unroll
            for (int er = 0; er < 8; ++er) WN[er] = wp[er * 64];
            wp += 512;
#pragma unroll
            for (int j = 0; j < NB; ++j) {
                xp[j] += ND;
                XN[j][0] = *(const float4*)xp[j];
                XN[j][1] = *(const float4*)(xp[j] + 4);
            }
        }

        // x -> half2 d-pairs
        h2 xq[NB][4];
#pragma unroll
        for (int j = 0; j < NB; ++j) {
            xq[j][0] = cvt_pk(XC[j][0].x, XC[j][0].y);
            xq[j][1] = cvt_pk(XC[j][0].z, XC[j][0].w);
            xq[j][2] = cvt_pk(XC[j][1].x, XC[j][1].y);
            xq[j][3] = cvt_pk(XC[j][1].z, XC[j][1].w);
        }

        // ---- u_hat (64 dot2) on current W registers ----
        float uh[NB][8];
#pragma unroll
        for (int er = 0; er < 8; ++er) {
            h2 w0 = u2h(WC[er].x), w1 = u2h(WC[er].y);
            h2 w2 = u2h(WC[er].z), w3 = u2h(WC[er].w);
#pragma unroll
            for (int j = 0; j < NB; ++j) {
                float acc = 0.f;
                acc = FDOT2(xq[j][0], w0, acc);
                acc = FDOT2(xq[j][1], w1, acc);
                acc = FDOT2(xq[j][2], w2, acc);
                acc = FDOT2(xq[j][3], w3, acc);
                uh[j][er] = acc;
            }
        }

        // ---- routing weights + s accumulation (all-VALU reductions) ----
        if (iter > 0) {
#pragma unroll
            for (int j = 0; j < NB; ++j) {
                float lp = 0.f;
#pragma unroll
                for (int e = 0; e < 8; ++e) lp = fmaf(uh[j][e], o_reg[j][e], lp);
                lp = xor32_sum(lp);                 // combine e-halves
                float el = __expf(lp);              // |logit| small; no max-sub
                float v = dpp_add<0x140>(dpp_add<0x141>(
                          dpp_add<0x4E>(dpp_add<0xB1>(el))));
                float den = xor16_sum(v);           // softmax denom over 32 c
                float wgt = el * __builtin_amdgcn_rcpf(den);
#pragma unroll
                for (int e = 0; e < 8; ++e) s_acc[j][e] = fmaf(wgt, uh[j][e], s_acc[j][e]);
            }
        } else {
            const float wgt = 1.f / 32.f;
#pragma unroll
            for (int j = 0; j < NB; ++j)
#pragma unroll
                for (int e = 0; e < 8; ++e) s_acc[j][e] = fmaf(wgt, uh[j][e], s_acc[j][e]);
        }
    };

    // 24 iterations, A/B double-buffer alternation for BOTH x and W
    for (int r2 = 0; r2 < ICHUNK / 2; ++r2) {
        body(xnA, xnB, wvA, wvB, 2 * r2);
        body(xnB, xnA, wvB, wvA, 2 * r2 + 1);
    }

    // ---- write partial s (fp16, one slice per ic) ----
#pragma unroll
    for (int j = 0; j < NB; ++j) {
        __half* base = s_part + (((size_t)ic * BATCH + (b0 + j)) * NC + c) * NE + e0;
        union { __half2 h2v[4]; uint4 u; } pk;
#pragma unroll
        for (int q = 0; q < 4; ++q)
            pk.h2v[q] = __floats2half2_rn(s_acc[j][2*q], s_acc[j][2*q+1]);
        *(uint4*)base = pk.u;
    }
}

// ---------------------------------------------------------------------------
// squash: reduce 48 fp16 slices, squash, update o_sum / write output.
// ---------------------------------------------------------------------------
__global__ __launch_bounds__(SQ_THREADS)
void squash_kernel(const __half* __restrict__ s_part, float* __restrict__ o_sum,
                   float* __restrict__ out, int iter)
{
    const int base2 = (blockIdx.x * SQ_THREADS + threadIdx.x) * 2;  // element pair

    float a0 = 0.f, a1 = 0.f;
#pragma unroll 8
    for (int k = 0; k < ISPLIT; ++k) {
        __half2 v = *(const __half2*)(s_part + (size_t)k * (BATCH * NC * NE) + base2);
        a0 += __low2float(v);
        a1 += __high2float(v);
    }

    float q = sum_over_e8(a0 * a0 + a1 * a1);
    // scale = s2/(1+s2)/sqrt(s2) == sqrt(s2)/(1+s2)
    float scale = sqrtf(q) / (1.f + q);
    float o0 = scale * a0, o1 = scale * a1;

    if (iter == NROUT - 1) {
        *(float2*)(out + base2) = make_float2(o0, o1);
    } else if (iter == 0) {
        *(float2*)(o_sum + base2) = make_float2(o0, o1);
    } else {
        float2 prev = *(float2*)(o_sum + base2);
        *(float2*)(o_sum + base2) = make_float2(prev.x + o0, prev.y + o1);
    }
}

extern "C" void kernel_launch(void* const* d_in, const int* in_sizes, int n_in,
                              void* d_out, int out_size, void* d_ws, size_t ws_size,
                              hipStream_t stream) {
    const float* x = (const float*)d_in[0];   // [128,1152,8]
    const float* W = (const float*)d_in[1];   // [1152,32,8,16]
    float* out = (float*)d_out;               // [128,32,16]

    // ws layout: [W_h 9.44 MB][s_part fp16 6.29 MB][o_sum 0.26 MB] = 15.99 MB
    uint4*  W_h    = (uint4*)d_ws;                                   // 1152*512 uint4
    __half* s_part = (__half*)(W_h + (size_t)NI * 512);              // 48*65536 half
    float*  o_sum  = (float*)(s_part + (size_t)ISPLIT * BATCH * NC * NE);

    prep_kernel<<<NI / PREP_TPB, RT_THREADS, 0, stream>>>(W, W_h);

    for (int it = 0; it < NROUT; ++it) {
        route_iter_kernel<<<dim3(ISPLIT, BATCH / BT), RT_THREADS, 0, stream>>>(
            x, W_h, o_sum, s_part, it);
        squash_kernel<<<(BATCH * NC * NE) / (SQ_THREADS * 2), SQ_THREADS, 0, stream>>>(
            s_part, o_sum, out, it);
    }
}

// Round 18
// 111.984 us; speedup vs baseline: 1.1141x; 1.0224x over previous
//
#include <hip/hip_runtime.h>
#include <hip/hip_fp16.h>
#include <math.h>

// Problem constants (from reference)
#define BATCH 128
#define NI    1152
#define ND    8
#define NC    32
#define NE    16
#define NROUT 3

// Structure: prep converts W once -> padded fp16 LDS-image tiles in ws.
// Route stages 8-tile groups into LDS with a LINEAR uint4 copy (no cvt, no
// transpose), then r14's barrier-free dot2 body reads W from LDS (broadcast
// across the block's waves -> per-block not per-wave global traffic).
// 69.6 KB LDS -> 2 blocks/CU. 256 thr = 32c x 2eh x 4bp; NB=2, BT=8
// -> grid 48 x 16 = 768 blocks.
#define ISPLIT     48
#define ICHUNK     (NI / ISPLIT)    // 24 tiles per block
#define GTILES     8                // tiles per stage group
#define NGROUP     (ICHUNK / GTILES) // 3
#define BT         8
#define NB         2
#define RT_THREADS 256
#define CROW       68               // words per c row (68%32=4 -> conflict-light)
#define TLDSW      (NC * CROW)      // 2176 words per padded tile (8704 B)
#define SQ_THREADS 256
#define PREP_TPB   2

typedef _Float16 h2 __attribute__((ext_vector_type(2)));
typedef unsigned int uint;

// cvt_pkrtz returns a __fp16 vector; bit-cast to h2 (_Float16 vector).
__device__ __forceinline__ h2 cvt_pk(float a, float b) {
    auto r = __builtin_amdgcn_cvt_pkrtz(a, b);
    union { decltype(r) i; h2 o; } u; u.i = r; return u.o;
}
__device__ __forceinline__ uint h2u(h2 v) { union { h2 h; uint u; } x; x.h = v; return x.u; }
__device__ __forceinline__ h2 u2h(uint v) { union { uint u; h2 h; } x; x.u = v; return x.h; }

#if __has_builtin(__builtin_amdgcn_fdot2)
#define FDOT2(a, b, c) __builtin_amdgcn_fdot2((a), (b), (c), false)
#else
__device__ __forceinline__ float FDOT2(h2 a, h2 b, float c) {
    return c + (float)a.x * (float)b.x + (float)a.y * (float)b.y;
}
#endif

template<int CTRL>
__device__ __forceinline__ float dpp_add(float v) {
    int t = __builtin_amdgcn_update_dpp(0, __float_as_int(v), CTRL, 0xF, 0xF, true);
    return v + __int_as_float(t);
}

// v[i] + v[i^32] — VALU permlane (fallback: shfl)
__device__ __forceinline__ float xor32_sum(float v) {
#if __has_builtin(__builtin_amdgcn_permlane32_swap)
    auto r = __builtin_amdgcn_permlane32_swap(__float_as_int(v), __float_as_int(v), false, false);
    return __int_as_float(r[0]) + __int_as_float(r[1]);
#else
    return v + __shfl_xor(v, 32);
#endif
}
// v[i] + v[i^16] — VALU permlane (fallback: ds_swizzle)
__device__ __forceinline__ float xor16_sum(float v) {
#if __has_builtin(__builtin_amdgcn_permlane16_swap)
    auto r = __builtin_amdgcn_permlane16_swap(__float_as_int(v), __float_as_int(v), false, false);
    return __int_as_float(r[0]) + __int_as_float(r[1]);
#else
    int s = __builtin_amdgcn_ds_swizzle(__float_as_int(v), 0x401F);
    return v + __int_as_float(s);
#endif
}

// Sum over lane bits 0..2 (8 e-pair lanes) for squash.
__device__ __forceinline__ float sum_over_e8(float v) {
    v = dpp_add<0xB1>(v);
    v = dpp_add<0x4E>(v);
    v = dpp_add<0x141>(v);
    return v;
}

// ---------------------------------------------------------------------------
// prep: W[i][c][d][e] fp32 -> padded fp16 tile image: word(c,e,dp) =
// c*68 + e*4 + dp within each 2176-word tile. Route copies these verbatim.
// ---------------------------------------------------------------------------
__global__ __launch_bounds__(RT_THREADS)
void prep_kernel(const float* __restrict__ W, uint* __restrict__ W_hp)
{
    __shared__ float ls[PREP_TPB][NC * 132];   // 33.8 KB

    const int tid = threadIdx.x;
    const size_t i0 = (size_t)blockIdx.x * PREP_TPB;

    const float4* src = (const float4*)(W + i0 * (NC * ND * NE));
#pragma unroll
    for (int t = 0; t < PREP_TPB; ++t) {
#pragma unroll
        for (int r = 0; r < 4; ++r) {
            int g = tid + r * RT_THREADS;              // 1024 float4 per tile
            float4 v = src[t * 1024 + g];
            *(float4*)&ls[t][(g >> 5) * 132 + (g & 31) * 4] = v;
        }
    }
    __syncthreads();

#pragma unroll
    for (int t = 0; t < PREP_TPB; ++t) {
#pragma unroll
        for (int r = 0; r < 2; ++r) {
            int g = tid + r * RT_THREADS;              // 512 (c,e) outputs/tile
            int c = g >> 4, e = g & 15;
            const float* p = &ls[t][c * 132 + e];      // stride 16 over d
            uint4 o;
            o.x = h2u(cvt_pk(p[0],  p[16]));           // d0,d1
            o.y = h2u(cvt_pk(p[32], p[48]));           // d2,d3
            o.z = h2u(cvt_pk(p[64], p[80]));           // d4,d5
            o.w = h2u(cvt_pk(p[96], p[112]));          // d6,d7
            *(uint4*)&W_hp[(i0 + t) * TLDSW + c * CROW + e * 4] = o;
        }
    }
}

// ---------------------------------------------------------------------------
// route: stage 8-tile groups (linear uint4 copy), then barrier-free dot2
// bodies reading W from LDS. x register double-buffered, laundered wave id.
// fp16 partial s out, one slice per ic.
// ---------------------------------------------------------------------------
__global__ __launch_bounds__(RT_THREADS)
void route_iter_kernel(const float* __restrict__ x, const uint* __restrict__ W_hp,
                       const float* __restrict__ o_sum, __half* __restrict__ s_part,
                       int iter)
{
    __shared__ uint Wh[GTILES * TLDSW];   // 69632 B -> 2 blocks/CU

    const int tid = threadIdx.x;
    const int c   = tid & 31;
    const int eh  = (tid >> 5) & 1;
    int wid;   // laundered wave id -> x addresses stay on the vector path
    asm("v_mov_b32 %0, %1" : "=v"(wid) : "v"(tid >> 6));
    const int ic  = blockIdx.x;
    const int bt  = blockIdx.y;
    const int i0  = ic * ICHUNK;
    const int b0  = bt * BT + wid * NB;
    const int e0  = eh * 8;

    // o_sum[b, c, e0..e0+7] in registers (iter > 0 only)
    float o_reg[NB][8];
    if (iter > 0) {
#pragma unroll
        for (int j = 0; j < NB; ++j) {
            const float4* op = (const float4*)(o_sum + ((size_t)(b0 + j) * NC + c) * NE + e0);
            float4 a = op[0], b = op[1];
            o_reg[j][0] = a.x; o_reg[j][1] = a.y; o_reg[j][2] = a.z; o_reg[j][3] = a.w;
            o_reg[j][4] = b.x; o_reg[j][5] = b.y; o_reg[j][6] = b.z; o_reg[j][7] = b.w;
        }
    }

    float s_acc[NB][8];
#pragma unroll
    for (int j = 0; j < NB; ++j)
#pragma unroll
        for (int e = 0; e < 8; ++e) s_acc[j][e] = 0.f;

    // x(0) prefetch (vector loads)
    const float* xp[NB];
    float4 xnA[NB][2], xnB[NB][2];
#pragma unroll
    for (int j = 0; j < NB; ++j) {
        xp[j] = x + ((size_t)(b0 + j) * NI + i0) * ND;
        xnA[j][0] = *(const float4*)xp[j];
        xnA[j][1] = *(const float4*)(xp[j] + 4);
    }

    const uint* wbase = &Wh[c * CROW + e0 * 4];

    auto body = [&](const float4 (&XC)[NB][2], float4 (&XN)[NB][2], int t, int II) {
        // issue x(II+1) into the other x register buffer
        if (II + 1 < ICHUNK) {
#pragma unroll
            for (int j = 0; j < NB; ++j) {
                xp[j] += ND;
                XN[j][0] = *(const float4*)xp[j];
                XN[j][1] = *(const float4*)(xp[j] + 4);
            }
        }

        // x -> half2 d-pairs
        h2 xq[NB][4];
#pragma unroll
        for (int j = 0; j < NB; ++j) {
            xq[j][0] = cvt_pk(XC[j][0].x, XC[j][0].y);
            xq[j][1] = cvt_pk(XC[j][0].z, XC[j][0].w);
            xq[j][2] = cvt_pk(XC[j][1].x, XC[j][1].y);
            xq[j][3] = cvt_pk(XC[j][1].z, XC[j][1].w);
        }

        // ---- u_hat from resident LDS tile t (8 b128, 64 dot2) ----
        const uint* wr = wbase + t * TLDSW;
        float uh[NB][8];
#pragma unroll
        for (int er = 0; er < 8; ++er) {
            uint4 wv = *(const uint4*)(wr + er * 4);
            h2 w0 = u2h(wv.x), w1 = u2h(wv.y), w2 = u2h(wv.z), w3 = u2h(wv.w);
#pragma unroll
            for (int j = 0; j < NB; ++j) {
                float acc = 0.f;
                acc = FDOT2(xq[j][0], w0, acc);
                acc = FDOT2(xq[j][1], w1, acc);
                acc = FDOT2(xq[j][2], w2, acc);
                acc = FDOT2(xq[j][3], w3, acc);
                uh[j][er] = acc;
            }
        }

        // ---- routing weights + s accumulation (all-VALU reductions) ----
        if (iter > 0) {
#pragma unroll
            for (int j = 0; j < NB; ++j) {
                float lp = 0.f;
#pragma unroll
                for (int e = 0; e < 8; ++e) lp = fmaf(uh[j][e], o_reg[j][e], lp);
                lp = xor32_sum(lp);                 // combine e-halves
                float el = __expf(lp);              // |logit| small; no max-sub
                float v = dpp_add<0x140>(dpp_add<0x141>(
                          dpp_add<0x4E>(dpp_add<0xB1>(el))));
                float den = xor16_sum(v);           // softmax denom over 32 c
                float wgt = el * __builtin_amdgcn_rcpf(den);
#pragma unroll
                for (int e = 0; e < 8; ++e) s_acc[j][e] = fmaf(wgt, uh[j][e], s_acc[j][e]);
            }
        } else {
            const float wgt = 1.f / 32.f;
#pragma unroll
            for (int j = 0; j < NB; ++j)
#pragma unroll
                for (int e = 0; e < 8; ++e) s_acc[j][e] = fmaf(wgt, uh[j][e], s_acc[j][e]);
        }
    };

    // 3 groups: {stage 8 tiles (linear copy), sync, 8 barrier-free bodies}
    for (int g = 0; g < NGROUP; ++g) {
        if (g) __syncthreads();          // previous group's readers done
        {
            const uint4* src = (const uint4*)(W_hp + (size_t)(i0 + g * GTILES) * TLDSW);
            uint4* dst = (uint4*)Wh;
#pragma unroll
            for (int k = 0; k < (GTILES * TLDSW / 4) / RT_THREADS; ++k)
                dst[tid + k * RT_THREADS] = src[tid + k * RT_THREADS];
        }
        __syncthreads();                 // staged tiles visible

#pragma unroll
        for (int tp = 0; tp < GTILES / 2; ++tp) {
            body(xnA, xnB, 2 * tp,     g * GTILES + 2 * tp);
            body(xnB, xnA, 2 * tp + 1, g * GTILES + 2 * tp + 1);
        }
    }

    // ---- write partial s (fp16, one slice per ic) ----
#pragma unroll
    for (int j = 0; j < NB; ++j) {
        __half* base = s_part + (((size_t)ic * BATCH + (b0 + j)) * NC + c) * NE + e0;
        union { __half2 h2v[4]; uint4 u; } pk;
#pragma unroll
        for (int q = 0; q < 4; ++q)
            pk.h2v[q] = __floats2half2_rn(s_acc[j][2*q], s_acc[j][2*q+1]);
        *(uint4*)base = pk.u;
    }
}

// ---------------------------------------------------------------------------
// squash: reduce 48 fp16 slices, squash, update o_sum / write output.
// ---------------------------------------------------------------------------
__global__ __launch_bounds__(SQ_THREADS)
void squash_kernel(const __half* __restrict__ s_part, float* __restrict__ o_sum,
                   float* __restrict__ out, int iter)
{
    const int base2 = (blockIdx.x * SQ_THREADS + threadIdx.x) * 2;  // element pair

    float a0 = 0.f, a1 = 0.f;
#pragma unroll 8
    for (int k = 0; k < ISPLIT; ++k) {
        __half2 v = *(const __half2*)(s_part + (size_t)k * (BATCH * NC * NE) + base2);
        a0 += __low2float(v);
        a1 += __high2float(v);
    }

    float q = sum_over_e8(a0 * a0 + a1 * a1);
    // scale = s2/(1+s2)/sqrt(s2) == sqrt(s2)/(1+s2)
    float scale = sqrtf(q) / (1.f + q);
    float o0 = scale * a0, o1 = scale * a1;

    if (iter == NROUT - 1) {
        *(float2*)(out + base2) = make_float2(o0, o1);
    } else if (iter == 0) {
        *(float2*)(o_sum + base2) = make_float2(o0, o1);
    } else {
        float2 prev = *(float2*)(o_sum + base2);
        *(float2*)(o_sum + base2) = make_float2(prev.x + o0, prev.y + o1);
    }
}

extern "C" void kernel_launch(void* const* d_in, const int* in_sizes, int n_in,
                              void* d_out, int out_size, void* d_ws, size_t ws_size,
                              hipStream_t stream) {
    const float* x = (const float*)d_in[0];   // [128,1152,8]
    const float* W = (const float*)d_in[1];   // [1152,32,8,16]
    float* out = (float*)d_out;               // [128,32,16]

    // ws: [W_hp padded fp16 tiles 10.03 MB][s_part fp16 6.29 MB][o_sum 0.26 MB]
    //   = 16.58 MB < 17.04 MB proven-available floor.
    uint*   W_hp   = (uint*)d_ws;                                    // 1152*2176 uints
    __half* s_part = (__half*)(W_hp + (size_t)NI * TLDSW);           // 48*65536 half
    float*  o_sum  = (float*)(s_part + (size_t)ISPLIT * BATCH * NC * NE);

    prep_kernel<<<NI / PREP_TPB, RT_THREADS, 0, stream>>>(W, W_hp);

    for (int it = 0; it < NROUT; ++it) {
        route_iter_kernel<<<dim3(ISPLIT, BATCH / BT), RT_THREADS, 0, stream>>>(
            x, W_hp, o_sum, s_part, it);
        squash_kernel<<<(BATCH * NC * NE) / (SQ_THREADS * 2), SQ_THREADS, 0, stream>>>(
            s_part, o_sum, out, it);
    }
}

// Round 19
// 106.100 us; speedup vs baseline: 1.1759x; 1.0555x over previous
//
#include <hip/hip_runtime.h>
#include <hip/hip_fp16.h>
#include <math.h>

// Problem constants (from reference)
#define BATCH 128
#define NI    1152
#define ND    8
#define NC    32
#define NE    16
#define NROUT 3

// Structure: prep converts W once -> padded fp16 LDS-image tiles in ws.
// Route stages GTILES-tile groups into LDS (linear uint4 copy), then
// barrier-free dot2 bodies (NB=4 batches/thread) read W from LDS.
// 256 thr = 32c x 2eh x 4bp; BT=16 -> grid ISPLIT x 8.
// Config A (ws >= 18.7MB): ISPLIT=64, GTILES=9 (78.3KB LDS) -> 512 blocks
//   = exactly 2 blocks/CU. Config B (fallback): ISPLIT=48, GTILES=8.
#define BT         16
#define NB         4
#define RT_THREADS 256
#define CROW       68               // words per c row (4c mod 32 -> uniform banks)
#define TLDSW      (NC * CROW)      // 2176 words per padded tile (8704 B)
#define SQ_THREADS 256
#define PREP_TPB   2

typedef _Float16 h2 __attribute__((ext_vector_type(2)));
typedef unsigned int uint;

__device__ __forceinline__ h2 cvt_pk(float a, float b) {
    auto r = __builtin_amdgcn_cvt_pkrtz(a, b);
    union { decltype(r) i; h2 o; } u; u.i = r; return u.o;
}
__device__ __forceinline__ uint h2u(h2 v) { union { h2 h; uint u; } x; x.h = v; return x.u; }
__device__ __forceinline__ h2 u2h(uint v) { union { uint u; h2 h; } x; x.u = v; return x.h; }

#if __has_builtin(__builtin_amdgcn_fdot2)
#define FDOT2(a, b, c) __builtin_amdgcn_fdot2((a), (b), (c), false)
#else
__device__ __forceinline__ float FDOT2(h2 a, h2 b, float c) {
    return c + (float)a.x * (float)b.x + (float)a.y * (float)b.y;
}
#endif

template<int CTRL>
__device__ __forceinline__ float dpp_add(float v) {
    int t = __builtin_amdgcn_update_dpp(0, __float_as_int(v), CTRL, 0xF, 0xF, true);
    return v + __int_as_float(t);
}

__device__ __forceinline__ float xor32_sum(float v) {
#if __has_builtin(__builtin_amdgcn_permlane32_swap)
    auto r = __builtin_amdgcn_permlane32_swap(__float_as_int(v), __float_as_int(v), false, false);
    return __int_as_float(r[0]) + __int_as_float(r[1]);
#else
    return v + __shfl_xor(v, 32);
#endif
}
__device__ __forceinline__ float xor16_sum(float v) {
#if __has_builtin(__builtin_amdgcn_permlane16_swap)
    auto r = __builtin_amdgcn_permlane16_swap(__float_as_int(v), __float_as_int(v), false, false);
    return __int_as_float(r[0]) + __int_as_float(r[1]);
#else
    int s = __builtin_amdgcn_ds_swizzle(__float_as_int(v), 0x401F);
    return v + __int_as_float(s);
#endif
}

__device__ __forceinline__ float sum_over_e8(float v) {
    v = dpp_add<0xB1>(v);
    v = dpp_add<0x4E>(v);
    v = dpp_add<0x141>(v);
    return v;
}

// ---------------------------------------------------------------------------
// prep: W[i][c][d][e] fp32 -> padded fp16 tile image (word c*68 + e*4 + dp).
// ---------------------------------------------------------------------------
__global__ __launch_bounds__(RT_THREADS)
void prep_kernel(const float* __restrict__ W, uint* __restrict__ W_hp)
{
    __shared__ float ls[PREP_TPB][NC * 132];

    const int tid = threadIdx.x;
    const size_t i0 = (size_t)blockIdx.x * PREP_TPB;

    const float4* src = (const float4*)(W + i0 * (NC * ND * NE));
#pragma unroll
    for (int t = 0; t < PREP_TPB; ++t) {
#pragma unroll
        for (int r = 0; r < 4; ++r) {
            int g = tid + r * RT_THREADS;
            float4 v = src[t * 1024 + g];
            *(float4*)&ls[t][(g >> 5) * 132 + (g & 31) * 4] = v;
        }
    }
    __syncthreads();

#pragma unroll
    for (int t = 0; t < PREP_TPB; ++t) {
#pragma unroll
        for (int r = 0; r < 2; ++r) {
            int g = tid + r * RT_THREADS;
            int c = g >> 4, e = g & 15;
            const float* p = &ls[t][c * 132 + e];
            uint4 o;
            o.x = h2u(cvt_pk(p[0],  p[16]));
            o.y = h2u(cvt_pk(p[32], p[48]));
            o.z = h2u(cvt_pk(p[64], p[80]));
            o.w = h2u(cvt_pk(p[96], p[112]));
            *(uint4*)&W_hp[(i0 + t) * TLDSW + c * CROW + e * 4] = o;
        }
    }
}

// ---------------------------------------------------------------------------
// route (templated on ISPLIT/GTILES): stage tile groups, barrier-free dot2
// bodies with NB=4, all-VALU softmax, fp16 partial s out.
// ---------------------------------------------------------------------------
template<int ISPLIT_T, int GTILES_T>
__global__ __launch_bounds__(RT_THREADS)
void route_iter_kernel(const float* __restrict__ x, const uint* __restrict__ W_hp,
                       const float* __restrict__ o_sum, __half* __restrict__ s_part,
                       int iter)
{
    constexpr int ICHUNK_T = NI / ISPLIT_T;
    constexpr int NGROUP_T = ICHUNK_T / GTILES_T;
    static_assert(NGROUP_T * GTILES_T == ICHUNK_T, "group split");

    __shared__ uint Wh[GTILES_T * TLDSW];

    const int tid = threadIdx.x;
    const int c   = tid & 31;
    const int eh  = (tid >> 5) & 1;
    int wid;   // laundered wave id -> x addresses stay on the vector path
    asm("v_mov_b32 %0, %1" : "=v"(wid) : "v"(tid >> 6));
    const int ic  = blockIdx.x;
    const int bt  = blockIdx.y;
    const int i0  = ic * ICHUNK_T;
    const int b0  = bt * BT + wid * NB;
    const int e0  = eh * 8;

    float o_reg[NB][8];
    if (iter > 0) {
#pragma unroll
        for (int j = 0; j < NB; ++j) {
            const float4* op = (const float4*)(o_sum + ((size_t)(b0 + j) * NC + c) * NE + e0);
            float4 a = op[0], b = op[1];
            o_reg[j][0] = a.x; o_reg[j][1] = a.y; o_reg[j][2] = a.z; o_reg[j][3] = a.w;
            o_reg[j][4] = b.x; o_reg[j][5] = b.y; o_reg[j][6] = b.z; o_reg[j][7] = b.w;
        }
    }

    float s_acc[NB][8];
#pragma unroll
    for (int j = 0; j < NB; ++j)
#pragma unroll
        for (int e = 0; e < 8; ++e) s_acc[j][e] = 0.f;

    // x(0) prefetch
    const float* xp[NB];
    float4 xnA[NB][2], xnB[NB][2];
#pragma unroll
    for (int j = 0; j < NB; ++j) {
        xp[j] = x + ((size_t)(b0 + j) * NI + i0) * ND;
        xnA[j][0] = *(const float4*)xp[j];
        xnA[j][1] = *(const float4*)(xp[j] + 4);
    }

    const uint* wbase = &Wh[c * CROW + e0 * 4];

    auto body = [&](const float4 (&XC)[NB][2], float4 (&XN)[NB][2], int t, int II) {
        if (II + 1 < ICHUNK_T) {
#pragma unroll
            for (int j = 0; j < NB; ++j) {
                xp[j] += ND;
                XN[j][0] = *(const float4*)xp[j];
                XN[j][1] = *(const float4*)(xp[j] + 4);
            }
        }

        h2 xq[NB][4];
#pragma unroll
        for (int j = 0; j < NB; ++j) {
            xq[j][0] = cvt_pk(XC[j][0].x, XC[j][0].y);
            xq[j][1] = cvt_pk(XC[j][0].z, XC[j][0].w);
            xq[j][2] = cvt_pk(XC[j][1].x, XC[j][1].y);
            xq[j][3] = cvt_pk(XC[j][1].z, XC[j][1].w);
        }

        // ---- u_hat from resident LDS tile t (8 b128, 128 dot2) ----
        const uint* wr = wbase + t * TLDSW;
        float uh[NB][8];
#pragma unroll
        for (int er = 0; er < 8; ++er) {
            uint4 wv = *(const uint4*)(wr + er * 4);
            h2 w0 = u2h(wv.x), w1 = u2h(wv.y), w2 = u2h(wv.z), w3 = u2h(wv.w);
#pragma unroll
            for (int j = 0; j < NB; ++j) {
                float acc = 0.f;
                acc = FDOT2(xq[j][0], w0, acc);
                acc = FDOT2(xq[j][1], w1, acc);
                acc = FDOT2(xq[j][2], w2, acc);
                acc = FDOT2(xq[j][3], w3, acc);
                uh[j][er] = acc;
            }
        }

        if (iter > 0) {
#pragma unroll
            for (int j = 0; j < NB; ++j) {
                float lp = 0.f;
#pragma unroll
                for (int e = 0; e < 8; ++e) lp = fmaf(uh[j][e], o_reg[j][e], lp);
                lp = xor32_sum(lp);
                float el = __expf(lp);
                float v = dpp_add<0x140>(dpp_add<0x141>(
                          dpp_add<0x4E>(dpp_add<0xB1>(el))));
                float den = xor16_sum(v);
                float wgt = el * __builtin_amdgcn_rcpf(den);
#pragma unroll
                for (int e = 0; e < 8; ++e) s_acc[j][e] = fmaf(wgt, uh[j][e], s_acc[j][e]);
            }
        } else {
            const float wgt = 1.f / 32.f;
#pragma unroll
            for (int j = 0; j < NB; ++j)
#pragma unroll
                for (int e = 0; e < 8; ++e) s_acc[j][e] = fmaf(wgt, uh[j][e], s_acc[j][e]);
        }
    };

    // groups: {stage GTILES tiles (linear copy), sync, GTILES bodies}
#pragma unroll
    for (int g = 0; g < NGROUP_T; ++g) {
        if (g) __syncthreads();
        {
            constexpr int TOT4 = GTILES_T * TLDSW / 4;
            const uint4* src = (const uint4*)(W_hp + (size_t)(i0 + g * GTILES_T) * TLDSW);
            uint4* dst = (uint4*)Wh;
#pragma unroll
            for (int k = 0; k < (TOT4 + RT_THREADS - 1) / RT_THREADS; ++k) {
                int idx = tid + k * RT_THREADS;
                if (TOT4 % RT_THREADS == 0 || idx < TOT4)
                    dst[idx] = src[idx];
            }
        }
        __syncthreads();

#pragma unroll
        for (int tp = 0; tp < GTILES_T; ++tp) {
            int II = g * GTILES_T + tp;
            if ((II & 1) == 0) body(xnA, xnB, tp, II);
            else               body(xnB, xnA, tp, II);
        }
    }

    // ---- write partial s (fp16, one slice per ic) ----
#pragma unroll
    for (int j = 0; j < NB; ++j) {
        __half* base = s_part + (((size_t)ic * BATCH + (b0 + j)) * NC + c) * NE + e0;
        union { __half2 h2v[4]; uint4 u; } pk;
#pragma unroll
        for (int q = 0; q < 4; ++q)
            pk.h2v[q] = __floats2half2_rn(s_acc[j][2*q], s_acc[j][2*q+1]);
        *(uint4*)base = pk.u;
    }
}

// ---------------------------------------------------------------------------
// squash: reduce nslice fp16 slices, squash, update o_sum / write output.
// ---------------------------------------------------------------------------
__global__ __launch_bounds__(SQ_THREADS)
void squash_kernel(const __half* __restrict__ s_part, float* __restrict__ o_sum,
                   float* __restrict__ out, int iter, int nslice)
{
    const int base2 = (blockIdx.x * SQ_THREADS + threadIdx.x) * 2;

    float a0 = 0.f, a1 = 0.f;
#pragma unroll 8
    for (int k = 0; k < nslice; ++k) {
        __half2 v = *(const __half2*)(s_part + (size_t)k * (BATCH * NC * NE) + base2);
        a0 += __low2float(v);
        a1 += __high2float(v);
    }

    float q = sum_over_e8(a0 * a0 + a1 * a1);
    // scale = s2/(1+s2)/sqrt(s2) == sqrt(s2)/(1+s2)
    float scale = sqrtf(q) / (1.f + q);
    float o0 = scale * a0, o1 = scale * a1;

    if (iter == NROUT - 1) {
        *(float2*)(out + base2) = make_float2(o0, o1);
    } else if (iter == 0) {
        *(float2*)(o_sum + base2) = make_float2(o0, o1);
    } else {
        float2 prev = *(float2*)(o_sum + base2);
        *(float2*)(o_sum + base2) = make_float2(prev.x + o0, prev.y + o1);
    }
}

extern "C" void kernel_launch(void* const* d_in, const int* in_sizes, int n_in,
                              void* d_out, int out_size, void* d_ws, size_t ws_size,
                              hipStream_t stream) {
    const float* x = (const float*)d_in[0];   // [128,1152,8]
    const float* W = (const float*)d_in[1];   // [1152,32,8,16]
    float* out = (float*)d_out;               // [128,32,16]

    const size_t whp_words  = (size_t)NI * TLDSW;                 // 10.03 MB
    const size_t slice_h    = (size_t)BATCH * NC * NE;            // 65536 halves

    uint*   W_hp   = (uint*)d_ws;
    __half* s_part = (__half*)(W_hp + whp_words);

    prep_kernel<<<NI / PREP_TPB, RT_THREADS, 0, stream>>>(W, W_hp);

    // Config A: ISPLIT=64 (512 blocks = 2/CU) if ws holds 64 fp16 slices.
    const size_t needA = whp_words * 4 + 64 * slice_h * 2 + slice_h * 4;
    if (ws_size >= needA) {
        float* o_sum = (float*)(s_part + 64 * slice_h);
        for (int it = 0; it < NROUT; ++it) {
            route_iter_kernel<64, 9><<<dim3(64, BATCH / BT), RT_THREADS, 0, stream>>>(
                x, W_hp, o_sum, s_part, it);
            squash_kernel<<<(BATCH * NC * NE) / (SQ_THREADS * 2), SQ_THREADS, 0, stream>>>(
                s_part, o_sum, out, it, 64);
        }
    } else {
        float* o_sum = (float*)(s_part + 48 * slice_h);
        for (int it = 0; it < NROUT; ++it) {
            route_iter_kernel<48, 8><<<dim3(48, BATCH / BT), RT_THREADS, 0, stream>>>(
                x, W_hp, o_sum, s_part, it);
            squash_kernel<<<(BATCH * NC * NE) / (SQ_THREADS * 2), SQ_THREADS, 0, stream>>>(
                s_part, o_sum, out, it, 48);
        }
    }
}